// Round 4
// baseline (498.363 us; speedup 1.0000x reference)
//
#include <hip/hip_runtime.h>

typedef unsigned short ushort_t;
typedef __attribute__((ext_vector_type(8))) short short8;
typedef __attribute__((ext_vector_type(4))) float f32x4;
typedef __attribute__((ext_vector_type(4))) float vf4;

// Problem constants (fixed by the reference)
constexpr int N_ATOMS = 50000;
constexpr int N_EDGES = 800000;
constexpr int ELEM    = 64;
constexpr int D_IN    = 192;   // 2*ELEM + NBR
constexpr int D_OUT   = 128;   // 2*ELEM
constexpr float EPS   = 1e-5f;

constexpr int TILE_M = 64;     // edges per GEMM block
constexpr int NREP   = 16;     // stat-accumulator replicas

// Workspace layout (bytes), 16B-aligned. Total ~122 MB.
constexpr size_t OFF_NS   = 0;                                        // f32 ns[N][64]
constexpr size_t OFF_ABF  = OFF_NS   + (size_t)N_ATOMS * ELEM * 4;    // bf16 atom_bf[N][64]
constexpr size_t OFF_NBF  = OFF_ABF  + (size_t)N_ATOMS * ELEM * 2;    // bf16 nbrf_bf[E][64]
constexpr size_t OFF_WT   = OFF_NBF  + (size_t)N_EDGES * ELEM * 2;    // bf16 Wt[128][192]
constexpr size_t OFF_BN1  = OFF_WT   + (size_t)D_OUT * D_IN * 2;      // f32 [NREP][256]
constexpr size_t OFF_BN2  = OFF_BN1  + NREP * 256 * 4;                // f32 [NREP][128]

__device__ __forceinline__ ushort_t f32_to_bf16(float f) {
    unsigned int u = __float_as_uint(f);
    u = (u + 0x7fffu + ((u >> 16) & 1u)) >> 16;   // RNE
    return (ushort_t)u;
}
__device__ __forceinline__ float softplus_f(float x) {
    return fmaxf(x, 0.f) + __logf(1.f + __expf(-fabsf(x)));
}

// ---- 0: prep + init: atom->bf16, W->Wt (bf16 transposed), zero ns + replicas ----
__global__ void prep_init_kernel(const float* __restrict__ atom, const float* __restrict__ W,
                                 ushort_t* __restrict__ abf, ushort_t* __restrict__ Wt,
                                 float* __restrict__ ns,
                                 float* __restrict__ bn1r, float* __restrict__ bn2r) {
    int i = blockIdx.x * blockDim.x + threadIdx.x;
    if (i < N_ATOMS * ELEM) { abf[i] = f32_to_bf16(atom[i]); ns[i] = 0.f; }
    if (i < D_IN * D_OUT) {
        int k = i >> 7, n = i & 127;                 // coalesced read of W[k][n]
        Wt[n * D_IN + k] = f32_to_bf16(W[i]);
    }
    if (i < NREP * 256) bn1r[i] = 0.f;
    if (i < NREP * 128) bn2r[i] = 0.f;
}

// gathered atom rows into As chunks 0/1 (128B/row, 8 threads/row)
__device__ __forceinline__ void stage_atoms(ushort_t (*As)[200],
                                            const ushort_t* __restrict__ abf,
                                            const int* __restrict__ sidx,
                                            const int* __restrict__ nidx,
                                            int e0, int tid) {
    #pragma unroll
    for (int ch = 0; ch < 2; ++ch) {
        const int* __restrict__ idx = ch ? nidx : sidx;
        #pragma unroll
        for (int i = 0; i < 2; ++i) {
            int r = (tid >> 3) + 32 * i;
            int h = tid & 7;
            const uint4* src = (const uint4*)(abf + (size_t)idx[e0 + r] * 64);
            *(uint4*)&As[r][ch * 64 + h * 8] = src[h];
        }
    }
}

// ---- 1: stats pass — gather+MFMA+bias, col sum/sumsq from regs; emit nbrf_bf ----
__global__ __launch_bounds__(256) void stats_kernel(
    const ushort_t* __restrict__ abf, const float* __restrict__ nbrf,
    const int* __restrict__ sidx, const int* __restrict__ nidx,
    const ushort_t* __restrict__ Wt, const float* __restrict__ bias,
    ushort_t* __restrict__ nbrf_bf, float* __restrict__ bn1r)
{
    __shared__ __align__(16) ushort_t As[64][200];   // 25.6 KB
    const int tid = threadIdx.x;
    const int e0  = blockIdx.x * TILE_M;

    stage_atoms(As, abf, sidx, nidx, e0, tid);
    // chunk 2: nbrf fp32 (nontemporal: single use) -> bf16 LDS + global byproduct
    #pragma unroll
    for (int i = 0; i < 4; ++i) {
        int r  = (tid >> 4) + 16 * i;
        int c4 = tid & 15;
        vf4 v = __builtin_nontemporal_load((const vf4*)(nbrf + (size_t)(e0 + r) * 64 + c4 * 4));
        ushort4 pk;
        pk.x = f32_to_bf16(v.x); pk.y = f32_to_bf16(v.y);
        pk.z = f32_to_bf16(v.z); pk.w = f32_to_bf16(v.w);
        *(ushort4*)&As[r][128 + c4 * 4] = pk;
        *(ushort4*)&nbrf_bf[(size_t)(e0 + r) * 64 + c4 * 4] = pk;
    }

    const int wave = tid >> 6, lane = tid & 63;
    const int m16 = lane & 15, quad = lane >> 4;

    f32x4 acc[4][2];
    #pragma unroll
    for (int mt = 0; mt < 4; ++mt)
        #pragma unroll
        for (int nt = 0; nt < 2; ++nt) acc[mt][nt] = (f32x4){0.f, 0.f, 0.f, 0.f};

    const ushort_t* bp0 = Wt + (size_t)(wave * 32 + m16) * D_IN + quad * 8;
    const ushort_t* bp1 = bp0 + 16 * D_IN;

    __syncthreads();

    // K in two halves of 3x32 to cap bfrag register pressure
    #pragma unroll
    for (int h = 0; h < 2; ++h) {
        short8 b0[3], b1[3];
        #pragma unroll
        for (int ks = 0; ks < 3; ++ks) {
            b0[ks] = *(const short8*)(bp0 + (h * 3 + ks) * 32);
            b1[ks] = *(const short8*)(bp1 + (h * 3 + ks) * 32);
        }
        #pragma unroll
        for (int ks = 0; ks < 3; ++ks) {
            int ko = (h * 3 + ks) * 32 + quad * 8;
            #pragma unroll
            for (int mt = 0; mt < 4; ++mt) {
                short8 a = *(const short8*)&As[mt * 16 + m16][ko];
                acc[mt][0] = __builtin_amdgcn_mfma_f32_16x16x32_bf16(a, b0[ks], acc[mt][0], 0, 0, 0);
                acc[mt][1] = __builtin_amdgcn_mfma_f32_16x16x32_bf16(a, b1[ks], acc[mt][1], 0, 0, 0);
            }
        }
    }

    // per-lane partial col stats over its 16 rows, butterfly over quad, atomics
    float* rep = bn1r + (size_t)(blockIdx.x & (NREP - 1)) * 256;
    #pragma unroll
    for (int nt = 0; nt < 2; ++nt) {
        int c = wave * 32 + nt * 16 + m16;
        float b = bias[c];
        float s = 0.f, q = 0.f;
        #pragma unroll
        for (int mt = 0; mt < 4; ++mt)
            #pragma unroll
            for (int r = 0; r < 4; ++r) {
                float v = acc[mt][nt][r] + b;
                s += v; q += v * v;
            }
        s += __shfl_xor(s, 16); s += __shfl_xor(s, 32);
        q += __shfl_xor(q, 16); q += __shfl_xor(q, 32);
        if (quad == 0) {
            atomicAdd(&rep[c], s);
            atomicAdd(&rep[128 + c], q);
        }
    }
}

// ---- 2: msg pass — recompute GEMM (bf16 inputs), gate in regs, segment-sum ----
// Wave w holds filter col 16w+m16 (nt=0) and core col 64+16w+m16 (nt=1).
// BN1 finalize is folded into the prologue (bn1r is L2-resident).
__global__ __launch_bounds__(256) void msg_kernel(
    const ushort_t* __restrict__ abf, const ushort_t* __restrict__ nbrf_bf,
    const int* __restrict__ sidx, const int* __restrict__ nidx,
    const ushort_t* __restrict__ Wt, const float* __restrict__ bias,
    const float* __restrict__ bn1r, const float* __restrict__ g1,
    const float* __restrict__ b1, float* __restrict__ ns)
{
    __shared__ __align__(16) char smem[25600];
    ushort_t (*As)[200] = (ushort_t(*)[200])smem;     // GEMM phase
    float    (*Ms)[68]  = (float(*)[68])smem;         // msg phase (aliases As)
    __shared__ int ss[64];
    __shared__ float scs[256];

    const int tid = threadIdx.x;
    const int e0  = blockIdx.x * TILE_M;

    // fold of bn1_finalize: per-block recompute of scale/shift (bias folded in)
    if (tid < 128) {
        int c = tid;
        float s = 0.f, q = 0.f;
        #pragma unroll
        for (int r = 0; r < NREP; ++r) { s += bn1r[r * 256 + c]; q += bn1r[r * 256 + 128 + c]; }
        float mean = s * (1.f / N_EDGES);
        float var  = q * (1.f / N_EDGES) - mean * mean;
        float scale = g1[c] * rsqrtf(var + EPS);
        scs[c] = scale;
        scs[128 + c] = fmaf(bias[c] - mean, scale, b1[c]);
    }

    stage_atoms(As, abf, sidx, nidx, e0, tid);
    // chunk 2 from bf16 byproduct: pure 16B copies (128B/row, 8 threads/row)
    #pragma unroll
    for (int i = 0; i < 2; ++i) {
        int r = (tid >> 3) + 32 * i;
        int h = tid & 7;
        const uint4* src = (const uint4*)(nbrf_bf + (size_t)(e0 + r) * 64);
        *(uint4*)&As[r][128 + h * 8] = src[h];
    }
    if (tid < 64) ss[tid] = sidx[e0 + tid];

    const int wave = tid >> 6, lane = tid & 63;
    const int m16 = lane & 15, quad = lane >> 4;
    const int cf = wave * 16 + m16;        // filter col 0..63
    const int cc = 64 + cf;                // core col 64..127

    f32x4 acc[4][2];
    #pragma unroll
    for (int mt = 0; mt < 4; ++mt)
        #pragma unroll
        for (int nt = 0; nt < 2; ++nt) acc[mt][nt] = (f32x4){0.f, 0.f, 0.f, 0.f};

    const ushort_t* bp0 = Wt + (size_t)cf * D_IN + quad * 8;
    const ushort_t* bp1 = Wt + (size_t)cc * D_IN + quad * 8;

    __syncthreads();

    #pragma unroll
    for (int h = 0; h < 2; ++h) {
        short8 b0[3], b1v[3];
        #pragma unroll
        for (int ks = 0; ks < 3; ++ks) {
            b0[ks]  = *(const short8*)(bp0 + (h * 3 + ks) * 32);
            b1v[ks] = *(const short8*)(bp1 + (h * 3 + ks) * 32);
        }
        #pragma unroll
        for (int ks = 0; ks < 3; ++ks) {
            int ko = (h * 3 + ks) * 32 + quad * 8;
            #pragma unroll
            for (int mt = 0; mt < 4; ++mt) {
                short8 a = *(const short8*)&As[mt * 16 + m16][ko];
                acc[mt][0] = __builtin_amdgcn_mfma_f32_16x16x32_bf16(a, b0[ks], acc[mt][0], 0, 0, 0);
                acc[mt][1] = __builtin_amdgcn_mfma_f32_16x16x32_bf16(a, b1v[ks], acc[mt][1], 0, 0, 0);
            }
        }
    }
    __syncthreads();   // done reading As — alias as Ms now

    // gate in registers, write msg tile to LDS
    {
        float scf = scs[cf], shf = scs[128 + cf];
        float scc = scs[cc], shc = scs[128 + cc];
        #pragma unroll
        for (int mt = 0; mt < 4; ++mt) {
            int row = mt * 16 + quad * 4;
            #pragma unroll
            for (int r = 0; r < 4; ++r) {
                float yf = fmaf(acc[mt][0][r], scf, shf);
                float yc = fmaf(acc[mt][1][r], scc, shc);
                Ms[row + r][cf] = softplus_f(yc) / (1.f + __expf(-yf));
            }
        }
    }
    __syncthreads();

    // run-detection segment sum (sidx sorted): thread (v,c) scans 16 rows of col c
    {
        int v = tid >> 6, c = tid & 63;
        int base = v * 16;
        int cur = ss[base];
        float a = 0.f;
        #pragma unroll
        for (int r = 0; r < 16; ++r) {
            int s = ss[base + r];
            if (s != cur) { atomicAdd(&ns[(size_t)cur * 64 + c], a); cur = s; a = 0.f; }
            a += Ms[base + r][c];
        }
        atomicAdd(&ns[(size_t)cur * 64 + c], a);
    }
}

// ---- 3: BN2 column stats (replicated atomics) ----
__global__ __launch_bounds__(256) void bn2_stats_kernel(
    const float* __restrict__ ns, float* __restrict__ bn2r)
{
    int c = threadIdx.x & 63;
    float s = 0.f, q = 0.f;
    for (int a = blockIdx.x * 4 + (threadIdx.x >> 6); a < N_ATOMS; a += 4096) {
        float v = ns[a * ELEM + c];
        s += v; q += v * v;
    }
    float* rep = bn2r + (size_t)(blockIdx.x & (NREP - 1)) * 128;
    atomicAdd(&rep[c], s);
    atomicAdd(&rep[64 + c], q);
}

// ---- 4: BN2 finalize (folded, per-block) + affine + residual + softplus ----
__global__ __launch_bounds__(256) void final_kernel(
    const float* __restrict__ atom, const float* __restrict__ ns,
    const float* __restrict__ bn2r, const float* __restrict__ g2,
    const float* __restrict__ b2, float* __restrict__ out)
{
    __shared__ float sc2s[128];
    int t = threadIdx.x;
    if (t < 64) {
        float s = 0.f, q = 0.f;
        #pragma unroll
        for (int r = 0; r < NREP; ++r) { s += bn2r[r * 128 + t]; q += bn2r[r * 128 + 64 + t]; }
        float mean = s * (1.f / N_ATOMS);
        float var  = q * (1.f / N_ATOMS) - mean * mean;
        float scale = g2[t] * rsqrtf(var + EPS);
        sc2s[t] = scale;
        sc2s[64 + t] = b2[t] - mean * scale;
    }
    __syncthreads();
    int i = blockIdx.x * 256 + t;
    if (i < N_ATOMS * ELEM) {
        int c = t & 63;
        float x = atom[i] + fmaf(ns[i], sc2s[c], sc2s[64 + c]);
        out[i] = softplus_f(x);
    }
}

extern "C" void kernel_launch(void* const* d_in, const int* in_sizes, int n_in,
                              void* d_out, int out_size, void* d_ws, size_t ws_size,
                              hipStream_t stream) {
    const float* atom = (const float*)d_in[0];
    const float* nbrf = (const float*)d_in[1];
    const int*   sidx = (const int*)d_in[2];
    const int*   nidx = (const int*)d_in[3];
    const float* W    = (const float*)d_in[4];
    const float* bias = (const float*)d_in[5];
    const float* g1   = (const float*)d_in[6];
    const float* b1   = (const float*)d_in[7];
    const float* g2   = (const float*)d_in[8];
    const float* b2   = (const float*)d_in[9];
    float* out = (float*)d_out;
    char*  ws  = (char*)d_ws;

    float*    ns    = (float*)(ws + OFF_NS);
    ushort_t* abf   = (ushort_t*)(ws + OFF_ABF);
    ushort_t* nbf   = (ushort_t*)(ws + OFF_NBF);
    ushort_t* Wt    = (ushort_t*)(ws + OFF_WT);
    float*    bn1r  = (float*)(ws + OFF_BN1);
    float*    bn2r  = (float*)(ws + OFF_BN2);

    hipLaunchKernelGGL(prep_init_kernel, dim3((N_ATOMS * ELEM + 255) / 256), dim3(256), 0, stream,
                       atom, W, abf, Wt, ns, bn1r, bn2r);
    hipLaunchKernelGGL(stats_kernel, dim3(N_EDGES / TILE_M), dim3(256), 0, stream,
                       abf, nbrf, sidx, nidx, Wt, bias, nbf, bn1r);
    hipLaunchKernelGGL(msg_kernel, dim3(N_EDGES / TILE_M), dim3(256), 0, stream,
                       abf, nbf, sidx, nidx, Wt, bias, bn1r, g1, b1, ns);
    hipLaunchKernelGGL(bn2_stats_kernel, dim3(1024), dim3(256), 0, stream, ns, bn2r);
    hipLaunchKernelGGL(final_kernel, dim3((N_ATOMS * ELEM + 255) / 256), dim3(256), 0, stream,
                       atom, ns, bn2r, g2, b2, out);
}